// Round 2
// baseline (344.013 us; speedup 1.0000x reference)
//
#include <hip/hip_runtime.h>

#define HH 1024
#define WW 1024
#define BH 64      // output rows per block
#define RAD 4

// Block: 256 threads, each owns 4 consecutive columns (float4 everywhere).
// Band of 64 rows, full 1024-wide. Fused separable 9x9 clipped box filter.
__global__ __launch_bounds__(256, 3) void box_kernel(const float* __restrict__ x,
                                                     float* __restrict__ out) {
    __shared__ __align__(16) float raw[2][WW + 8];   // zero halo of 4 each side
    __shared__ __align__(16) float hring[9][WW];     // ring of horizontal sums

    const int tid = threadIdx.x;
    const int img = blockIdx.y;
    const int r0  = blockIdx.x * BH;
    const int c   = tid * 4;

    const float* xin = x + (size_t)img * HH * WW;
    float*       o   = out + (size_t)img * HH * WW;

    // zero the column halos once (visible after first __syncthreads)
    if (tid < 4) {
        raw[0][tid] = 0.f; raw[1][tid] = 0.f;
        raw[0][WW + 4 + tid] = 0.f; raw[1][WW + 4 + tid] = 0.f;
    }

    // per-column horizontal counts (constant over rows)
    float inv_cw[4];
#pragma unroll
    for (int j = 0; j < 4; ++j) {
        int cc = c + j;
        int lo = cc - RAD < 0 ? 0 : cc - RAD;
        int hi = cc + RAD > WW - 1 ? WW - 1 : cc + RAD;
        inv_cw[j] = 1.0f / (float)(hi - lo + 1);
    }

    float vs0 = 0.f, vs1 = 0.f, vs2 = 0.f, vs3 = 0.f;
    int p = 0;

    // ---- prime: rows r0-5 .. r0+3 into ring slots 0..8, ALL accumulated ----
    // Invariant entering main loop at r=r0: vs = sum of h over rows r0-5..r0+3,
    // so vs += h(r+4) - h(r-5) yields the window r-4..r+4.
#pragma unroll 1
    for (int k = 0; k < 9; ++k) {
        int rr = r0 - 5 + k;
        float4 v;
        if (rr >= 0) v = *(const float4*)(xin + (size_t)rr * WW + c);
        else         v = make_float4(0.f, 0.f, 0.f, 0.f);
        *(float4*)&raw[p][4 + c] = v;
        __syncthreads();
        float4 a = *(const float4*)&raw[p][c];
        float4 b = *(const float4*)&raw[p][c + 4];
        float4 d = *(const float4*)&raw[p][c + 8];
        float h0 = ((a.x + a.y) + (a.z + a.w)) + ((b.x + b.y) + (b.z + b.w)) + d.x;
        float h1 = h0 - a.x + d.y;
        float h2 = h1 - a.y + d.z;
        float h3 = h2 - a.z + d.w;
        *(float4*)&hring[k][c] = make_float4(h0, h1, h2, h3);
        vs0 += h0; vs1 += h1; vs2 += h2; vs3 += h3;
        p ^= 1;
    }

    // ---- main: 64 output rows ----
    int slot = 0;
#pragma unroll 1
    for (int r = r0; r < r0 + BH; ++r) {
        int rl = r + RAD;
        float4 v;
        if (rl < HH) v = *(const float4*)(xin + (size_t)rl * WW + c);
        else         v = make_float4(0.f, 0.f, 0.f, 0.f);
        *(float4*)&raw[p][4 + c] = v;
        __syncthreads();
        float4 a = *(const float4*)&raw[p][c];
        float4 b = *(const float4*)&raw[p][c + 4];
        float4 d = *(const float4*)&raw[p][c + 8];
        float h0 = ((a.x + a.y) + (a.z + a.w)) + ((b.x + b.y) + (b.z + b.w)) + d.x;
        float h1 = h0 - a.x + d.y;
        float h2 = h1 - a.y + d.z;
        float h3 = h2 - a.z + d.w;

        // vertical running sum: subtract row r-5, add row r+4 (same ring slot)
        float4 hold = *(const float4*)&hring[slot][c];
        vs0 += h0 - hold.x;
        vs1 += h1 - hold.y;
        vs2 += h2 - hold.z;
        vs3 += h3 - hold.w;
        *(float4*)&hring[slot][c] = make_float4(h0, h1, h2, h3);
        slot = (slot == 8) ? 0 : slot + 1;

        int lo = r - RAD < 0 ? 0 : r - RAD;
        int hi = r + RAD > HH - 1 ? HH - 1 : r + RAD;
        float inv_ch = 1.0f / (float)(hi - lo + 1);

        float4 o4 = make_float4(vs0 * inv_ch * inv_cw[0],
                                vs1 * inv_ch * inv_cw[1],
                                vs2 * inv_ch * inv_cw[2],
                                vs3 * inv_ch * inv_cw[3]);
        *(float4*)(o + (size_t)r * WW + c) = o4;
        p ^= 1;
    }
}

extern "C" void kernel_launch(void* const* d_in, const int* in_sizes, int n_in,
                              void* d_out, int out_size, void* d_ws, size_t ws_size,
                              hipStream_t stream) {
    const float* x = (const float*)d_in[0];
    float* out = (float*)d_out;
    int n_images = in_sizes[0] / (HH * WW);   // 16*3 = 48
    dim3 grid(HH / BH, n_images);             // 16 x 48 = 768 blocks
    dim3 block(256);
    box_kernel<<<grid, block, 0, stream>>>(x, out);
}

// Round 3
// 343.466 us; speedup vs baseline: 1.0016x; 1.0016x over previous
//
#include <hip/hip_runtime.h>

#define HH 1024
#define WW 1024
#define BH 64      // output rows per block
#define RAD 4

// 256 threads/block, each owns 4 consecutive columns. Fused separable 9x9
// clipped box filter, BARRIER-FREE:
//  - horizontal halo via overlapping global float4 loads (L1/L2 absorb the 3x
//    request amplification; HBM fetch stays ~1x)
//  - vertical 9-row ring of horizontal sums in LDS, but every slot is written
//    and read only by the owning thread -> no __syncthreads anywhere.
__global__ __launch_bounds__(256) void box_kernel(const float* __restrict__ x,
                                                  float* __restrict__ out) {
    __shared__ __align__(16) float hring[9][WW];   // 36 KB

    const int tid = threadIdx.x;
    const int img = blockIdx.y;
    const int r0  = blockIdx.x * BH;
    const int c   = tid * 4;

    const float* xin = x + (size_t)img * HH * WW;
    float*       o   = out + (size_t)img * HH * WW;

    // per-column horizontal counts (constant over rows)
    float inv_cw[4];
#pragma unroll
    for (int j = 0; j < 4; ++j) {
        int cc = c + j;
        int lo = cc - RAD < 0 ? 0 : cc - RAD;
        int hi = cc + RAD > WW - 1 ? WW - 1 : cc + RAD;
        inv_cw[j] = 1.0f / (float)(hi - lo + 1);
    }

    const bool first = (tid == 0);
    const bool last  = (tid == 255);

    float vs0 = 0.f, vs1 = 0.f, vs2 = 0.f, vs3 = 0.f;

    // ---- prime: rows r0-5 .. r0+3 into ring slots 0..8, all accumulated ----
#pragma unroll 1
    for (int k = 0; k < 9; ++k) {
        int rr = r0 - 5 + k;
        float4 a, b, d;
        if (rr >= 0) {   // rr <= r0+3 <= 1023 always
            const float* row = xin + (size_t)rr * WW;
            b = *(const float4*)(row + c);
            a = first ? make_float4(0.f,0.f,0.f,0.f) : *(const float4*)(row + c - 4);
            d = last  ? make_float4(0.f,0.f,0.f,0.f) : *(const float4*)(row + c + 4);
        } else {
            a = b = d = make_float4(0.f,0.f,0.f,0.f);
        }
        float h0 = ((a.x + a.y) + (a.z + a.w)) + ((b.x + b.y) + (b.z + b.w)) + d.x;
        float h1 = h0 - a.x + d.y;
        float h2 = h1 - a.y + d.z;
        float h3 = h2 - a.z + d.w;
        *(float4*)&hring[k][c] = make_float4(h0, h1, h2, h3);
        vs0 += h0; vs1 += h1; vs2 += h2; vs3 += h3;
    }

    // ---- main: 64 output rows, no barriers ----
    int slot = 0;
#pragma unroll 2
    for (int r = r0; r < r0 + BH; ++r) {
        int rl = r + RAD;
        float4 a, b, d;
        if (rl < HH) {
            const float* row = xin + (size_t)rl * WW;
            b = *(const float4*)(row + c);
            a = first ? make_float4(0.f,0.f,0.f,0.f) : *(const float4*)(row + c - 4);
            d = last  ? make_float4(0.f,0.f,0.f,0.f) : *(const float4*)(row + c + 4);
        } else {
            a = b = d = make_float4(0.f,0.f,0.f,0.f);
        }
        float h0 = ((a.x + a.y) + (a.z + a.w)) + ((b.x + b.y) + (b.z + b.w)) + d.x;
        float h1 = h0 - a.x + d.y;
        float h2 = h1 - a.y + d.z;
        float h3 = h2 - a.z + d.w;

        // vertical running sum: subtract row r-5 (ring), add row r+4
        float4 hold = *(const float4*)&hring[slot][c];
        vs0 += h0 - hold.x;
        vs1 += h1 - hold.y;
        vs2 += h2 - hold.z;
        vs3 += h3 - hold.w;
        *(float4*)&hring[slot][c] = make_float4(h0, h1, h2, h3);
        slot = (slot == 8) ? 0 : slot + 1;

        int lo = r - RAD < 0 ? 0 : r - RAD;
        int hi = r + RAD > HH - 1 ? HH - 1 : r + RAD;
        float inv_ch = 1.0f / (float)(hi - lo + 1);

        float4 o4 = make_float4(vs0 * inv_ch * inv_cw[0],
                                vs1 * inv_ch * inv_cw[1],
                                vs2 * inv_ch * inv_cw[2],
                                vs3 * inv_ch * inv_cw[3]);
        *(float4*)(o + (size_t)r * WW + c) = o4;
    }
}

extern "C" void kernel_launch(void* const* d_in, const int* in_sizes, int n_in,
                              void* d_out, int out_size, void* d_ws, size_t ws_size,
                              hipStream_t stream) {
    const float* x = (const float*)d_in[0];
    float* out = (float*)d_out;
    int n_images = in_sizes[0] / (HH * WW);   // 16*3 = 48
    dim3 grid(HH / BH, n_images);             // 16 x 48 = 768 blocks
    dim3 block(256);
    box_kernel<<<grid, block, 0, stream>>>(x, out);
}